// Round 11
// baseline (269.575 us; speedup 1.0000x reference)
//
#include <hip/hip_runtime.h>
#include <hip/hip_bf16.h>
#include <cstdint>

#define HD 128
#define BKSZ 256          // nodes per bucket
#define BCAP 12288        // bucket capacity (mean fill 8163, ~45 sigma headroom)

typedef __attribute__((ext_vector_type(8))) short bfx8;   // 8 bf16 in 4 VGPRs
typedef __attribute__((ext_vector_type(4))) float fx4;

__device__ inline float bf2f(short s) {
    union { uint32_t u; float f; } c;
    c.u = ((uint32_t)(unsigned short)s) << 16;
    return c.f;
}
__device__ inline unsigned short f2bf(float v) {
    union { float f; uint32_t u; } c;
    c.f = v;
    uint32_t u = c.u + 0x7FFF + ((c.u >> 16) & 1);   // RNE
    return (unsigned short)(u >> 16);
}

// async global->LDS staging: no VGPR destinations -> deep MLP regardless of
// register budget (m97 mechanism). Layout must be linear on both sides.
__device__ inline void stage_lds(const void* g, void* l, int nbytes) {
    const char* gc = (const char*)g;
    for (int off = threadIdx.x * 16; off < nbytes; off += 4096) {
        __builtin_amdgcn_global_load_lds(
            (const __attribute__((address_space(1))) unsigned int*)(gc + off),
            (__attribute__((address_space(3))) unsigned int*)
                ((__attribute__((address_space(3))) char*)l + off),
            16, 0, 0);
    }
}

// ---------------- bucketed CSR build ----------------
// bucket b = dst >> 8 (256 nodes/bucket, NBK = 196). Edge packed into one word:
// (dst & 255) << 24 | src   (requires src < 2^24 — N = 50000).

__global__ void k_zero(int* __restrict__ p, int n) {
    int i = blockIdx.x * 256 + threadIdx.x;
    if (i < n) p[i] = 0;
}

// Phase 1: LDS-aggregated binning; one packed 4B write per edge.
__global__ __launch_bounds__(256) void k_bin(const int* __restrict__ ei, int E, int NBK,
                                             int* __restrict__ bcnt,
                                             int* __restrict__ bpack) {
    __shared__ int lhist[BKSZ];
    __shared__ int gbase[BKSZ];
    int base = blockIdx.x * 4096;

    for (int i = threadIdx.x; i < NBK; i += 256) lhist[i] = 0;
    __syncthreads();

    int pw[16];
    int meta[16];
    const int4* s4 = (const int4*)ei;
    const int4* d4 = (const int4*)(ei + E);
    int c0 = base >> 2;
    int EC = E >> 2;                       // E % 4 == 0
#pragma unroll
    for (int j = 0; j < 4; ++j) {
        int c4 = c0 + j * 256 + threadIdx.x;
        bool ok = (c4 < EC);
        int4 sv = make_int4(0, 0, 0, 0), dv = make_int4(0, 0, 0, 0);
        if (ok) { sv = s4[c4]; dv = d4[c4]; }
        int ss[4] = {sv.x, sv.y, sv.z, sv.w};
        int dd[4] = {dv.x, dv.y, dv.z, dv.w};
#pragma unroll
        for (int l = 0; l < 4; ++l) {
            int idx = j * 4 + l;
            meta[idx] = -1;
            if (ok) {
                int d = dd[l];
                int b = d >> 8;
                int lr = atomicAdd(&lhist[b], 1);          // LDS atomic
                pw[idx]   = ((d & 255) << 24) | ss[l];
                meta[idx] = (b << 16) | lr;                // b<=195, lr<4096
            }
        }
    }
    __syncthreads();
    for (int i = threadIdx.x; i < NBK; i += 256) {
        int c = lhist[i];
        gbase[i] = c ? atomicAdd(&bcnt[i], c) : 0;         // 1 global atomic/bucket
    }
    __syncthreads();
#pragma unroll
    for (int idx = 0; idx < 16; ++idx) {
        int m = meta[idx];
        if (m >= 0) {
            int b = m >> 16, lr = m & 0xFFFF;
            int pos = b * BCAP + min(gbase[b] + lr, BCAP - 1);  // clamp: no OOB
            bpack[pos] = pw[idx];
        }
    }
}

// Phase 2: exclusive scan of bucket counts (NBK <= 1024, one block)
__global__ __launch_bounds__(1024) void k_bscan(const int* __restrict__ bcnt,
                                                int* __restrict__ boff, int NBK, int E) {
    __shared__ int sh[1024];
    int t = threadIdx.x;
    int v = (t < NBK) ? bcnt[t] : 0;
    sh[t] = v;
    __syncthreads();
    for (int d = 1; d < 1024; d <<= 1) {
        int o = (t >= d) ? sh[t - d] : 0;
        __syncthreads();
        sh[t] += o;
        __syncthreads();
    }
    if (t < NBK) boff[t] = sh[t] - v;     // exclusive
    if (t == 0) boff[NBK] = E;
}

// Phase 3: per-bucket local sort (256 LDS counters).
__global__ __launch_bounds__(256) void k_bucket(const int* __restrict__ bpack,
                                                const int* __restrict__ bcnt,
                                                const int* __restrict__ boff,
                                                int* __restrict__ offsets,
                                                int* __restrict__ sorted,
                                                int N, int E) {
    __shared__ int lh[BKSZ];
    __shared__ int cur[BKSZ];
    __shared__ int wsum[4];
    int b = blockIdx.x;
    int cnt = min(bcnt[b], BCAP);
    int base = b * BCAP;
    int obase = boff[b];
    int tid = threadIdx.x;

    lh[tid] = 0;
    __syncthreads();
    for (int i = tid; i < cnt; i += 256)
        atomicAdd(&lh[((unsigned)bpack[base + i]) >> 24], 1);
    __syncthreads();

    // 256-entry exclusive scan: intra-wave shfl + cross-wave prefix
    int v = lh[tid];
    int sum = v;
#pragma unroll
    for (int s = 1; s < 64; s <<= 1) {
        int o = __shfl_up(sum, s, 64);
        if ((tid & 63) >= s) sum += o;
    }
    int wid = tid >> 6;
    if ((tid & 63) == 63) wsum[wid] = sum;
    __syncthreads();
    int prefix = 0;
#pragma unroll
    for (int w = 0; w < 4; ++w)
        if (w < wid) prefix += wsum[w];
    int excl = prefix + sum - v;
    int n = b * BKSZ + tid;
    if (n < N) offsets[n] = obase + excl;
    cur[tid] = excl;
    __syncthreads();

    for (int i = tid; i < cnt; i += 256) {
        int w = bpack[base + i];
        int ln = ((unsigned)w) >> 24;
        int p = atomicAdd(&cur[ln], 1);          // LDS atomic
        sorted[obase + p] = w & 0xFFFFFF;
    }
    if (b == 0 && tid == 0) offsets[N] = E;
}

// ---------------- fp32 -> bf16 casts ----------------

__global__ void k_cast(const float* __restrict__ in, unsigned short* __restrict__ out,
                       int n8) {
    int i = blockIdx.x * 256 + threadIdx.x;
    if (i >= n8) return;
    float4 v0 = ((const float4*)in)[i * 2];
    float4 v1 = ((const float4*)in)[i * 2 + 1];
    bfx8 o;
    o[0] = (short)f2bf(v0.x); o[1] = (short)f2bf(v0.y);
    o[2] = (short)f2bf(v0.z); o[3] = (short)f2bf(v0.w);
    o[4] = (short)f2bf(v1.x); o[5] = (short)f2bf(v1.y);
    o[6] = (short)f2bf(v1.z); o[7] = (short)f2bf(v1.w);
    *(bfx8*)(out + (size_t)i * 8) = o;
}

// five 128x128 weights -> bf16 in FRAGMENT-MAJOR order:
// slot s = (kk*8+cf)*64 + l  holds  W[cf*16+(l&15)][kk*32+(l>>4)*8 .. +7].
// Makes GEMM-side LDS staging linear and weight ds_read_b128 stride-1.
__global__ void k_cast5(const float* __restrict__ w0, const float* __restrict__ w1,
                        const float* __restrict__ w2, const float* __restrict__ w3,
                        const float* __restrict__ w4, unsigned short* __restrict__ out) {
    int t = blockIdx.x * 256 + threadIdx.x;   // 5 * 2048 slots
    if (t >= 5 * 2048) return;
    int m = t / 2048, s = t % 2048;
    const float* src = (m == 0) ? w0 : (m == 1) ? w1 : (m == 2) ? w2 : (m == 3) ? w3 : w4;
    int l  = s & 63;
    int fi = s >> 6;          // 0..31
    int kk = fi >> 3;
    int cf = fi & 7;
    int r  = l & 15;
    int hi = l >> 4;
    int row  = cf * 16 + r;
    int col0 = kk * 32 + hi * 8;
    const float4* sp = (const float4*)(src + row * HD + col0);   // 32B aligned
    float4 v0 = sp[0];
    float4 v1 = sp[1];
    bfx8 o;
    o[0] = (short)f2bf(v0.x); o[1] = (short)f2bf(v0.y);
    o[2] = (short)f2bf(v0.z); o[3] = (short)f2bf(v0.w);
    o[4] = (short)f2bf(v1.x); o[5] = (short)f2bf(v1.y);
    o[6] = (short)f2bf(v1.z); o[7] = (short)f2bf(v1.w);
    *(bfx8*)(out + (size_t)t * 8) = o;
}

// ---------------- mean aggregation: one wave per node, deep-MLP gather ----------------
// 4 slots x 16 lanes; slot q owns a CONTIGUOUS chunk of the node's edge range:
// adjacent index loads (same line) + 8 independent 256B row loads in flight.

__global__ __launch_bounds__(256) void k_aggr(const unsigned short* __restrict__ x,
                                              const int* __restrict__ offsets,
                                              const int* __restrict__ sorted_src,
                                              unsigned short* __restrict__ out, int N) {
    int wid  = threadIdx.x >> 6;
    int lane = threadIdx.x & 63;
    int n = blockIdx.x * 4 + wid;
    if (n >= N) return;
    int slot = lane >> 4;     // 0..3
    int c    = lane & 15;     // feature octet
    int beg = offsets[n], end = offsets[n + 1];
    int deg = end - beg;

    int chunk = (deg + 3) >> 2;
    int e  = beg + slot * chunk;
    int s1 = min(e + chunk, end);

    float acc[8];
#pragma unroll
    for (int j = 0; j < 8; ++j) acc[j] = 0.f;

    // 8-deep: 8 adjacent index loads, then 8 independent row loads in flight
    while (e + 8 <= s1) {
        int idx[8];
#pragma unroll
        for (int u = 0; u < 8; ++u) idx[u] = sorted_src[e + u];
        bfx8 v[8];
#pragma unroll
        for (int u = 0; u < 8; ++u)
            v[u] = *(const bfx8*)(x + (size_t)idx[u] * HD + c * 8);
#pragma unroll
        for (int u = 0; u < 8; ++u)
#pragma unroll
            for (int j = 0; j < 8; ++j) acc[j] += bf2f(v[u][j]);
        e += 8;
    }
    if (e + 4 <= s1) {
        int idx[4];
#pragma unroll
        for (int u = 0; u < 4; ++u) idx[u] = sorted_src[e + u];
        bfx8 v[4];
#pragma unroll
        for (int u = 0; u < 4; ++u)
            v[u] = *(const bfx8*)(x + (size_t)idx[u] * HD + c * 8);
#pragma unroll
        for (int u = 0; u < 4; ++u)
#pragma unroll
            for (int j = 0; j < 8; ++j) acc[j] += bf2f(v[u][j]);
        e += 4;
    }
    for (; e < s1; ++e) {
        int i0 = sorted_src[e];
        bfx8 v0 = *(const bfx8*)(x + (size_t)i0 * HD + c * 8);
#pragma unroll
        for (int j = 0; j < 8; ++j) acc[j] += bf2f(v0[j]);
    }

#pragma unroll
    for (int j = 0; j < 8; ++j) {
        acc[j] += __shfl_xor(acc[j], 16, 64);
        acc[j] += __shfl_xor(acc[j], 32, 64);
    }
    if (slot == 0) {
        float inv = 1.f / fmaxf((float)deg, 1.f);
        bfx8 o;
#pragma unroll
        for (int j = 0; j < 8; ++j) o[j] = (short)f2bf(acc[j] * inv);
        *(bfx8*)(out + (size_t)n * HD + c * 8) = o;
    }
}

// ---------------- layer-1 MFMA dual GEMM (LDS-staged weights) ----------------
// Wl+Wr (64KB, fragment-major) staged to LDS via global_load_lds once/block;
// all 4 waves share them. Weight ds_read_b128 is stride-1 (conflict-free).
// mfma_f32_16x16x32_bf16: A lane: row=l&15, k=(l>>4)*8+j ; B lane: col=l&15 ;
// D: col=l&15, row=(l>>4)*4+reg  [m89-verified].

__global__ __launch_bounds__(256) void k_gemm_mfma(
    const unsigned short* __restrict__ A,
    const unsigned short* __restrict__ B,
    const unsigned short* __restrict__ Wl,   // fragment-major
    const unsigned short* __restrict__ Wr,   // fragment-major
    const float* __restrict__ bias,
    unsigned short* __restrict__ outb, int nrows) {
    __shared__ bfx8 ldsW[4096];              // 64 KB: [0..2048)=Wl, [2048..4096)=Wr

    int wid  = threadIdx.x >> 6;
    int lane = threadIdx.x & 63;
    int r  = lane & 15;
    int hi = lane >> 4;          // 0..3
    int ko = hi * 8;
    int row0 = blockIdx.x * 64 + wid * 16;

    int arow  = row0 + r;
    int arowc = min(arow, nrows - 1);

    // issue per-lane A/B row loads first (latency overlaps the staging)
    bfx8 a[4], b[4];
    const unsigned short* Ar = A + (size_t)arowc * HD;
    const unsigned short* Br = B + (size_t)arowc * HD;
#pragma unroll
    for (int kk = 0; kk < 4; ++kk) {
        a[kk] = *(const bfx8*)(Ar + kk * 32 + ko);
        b[kk] = *(const bfx8*)(Br + kk * 32 + ko);
    }

    stage_lds(Wl, &ldsW[0],    32768);
    stage_lds(Wr, &ldsW[2048], 32768);

    float bv[8];
#pragma unroll
    for (int cf = 0; cf < 8; ++cf) bv[cf] = bias[cf * 16 + r];

    fx4 acc[8];
#pragma unroll
    for (int cf = 0; cf < 8; ++cf) acc[cf] = (fx4){0.f, 0.f, 0.f, 0.f};

    __syncthreads();   // drains global_load_lds (vmcnt) + all waves see LDS

#pragma unroll
    for (int kk = 0; kk < 4; ++kk) {
#pragma unroll
        for (int cf = 0; cf < 8; ++cf) {
            acc[cf] = __builtin_amdgcn_mfma_f32_16x16x32_bf16(
                a[kk], ldsW[(kk * 8 + cf) * 64 + lane], acc[cf], 0, 0, 0);
            acc[cf] = __builtin_amdgcn_mfma_f32_16x16x32_bf16(
                b[kk], ldsW[2048 + (kk * 8 + cf) * 64 + lane], acc[cf], 0, 0, 0);
        }
    }

#pragma unroll
    for (int cf = 0; cf < 8; ++cf) {
#pragma unroll
        for (int j = 0; j < 4; ++j) {
            int row = row0 + hi * 4 + j;
            if (row < nrows)
                outb[(size_t)row * HD + cf * 16 + r] = f2bf(fmaxf(acc[cf][j] + bv[cf], 0.f));
        }
    }
}

// ---------------- fused layer2 + MLP + final dot (LDS-staged weights) ----------------
// Stage W2l+W2r -> compute h2 -> hlds; reload Mw1 into same LDS; stage-2 GEMM
// + fused mw2 dot. hlds swizzle: byte ^= (row&7)<<4 (stride-256B column reads).

__global__ __launch_bounds__(256) void k_l2_fused(
    const unsigned short* __restrict__ A,     // aggr2
    const unsigned short* __restrict__ B,     // h1
    const unsigned short* __restrict__ Wl,    // w2l fragment-major
    const unsigned short* __restrict__ Wr,    // w2r fragment-major
    const float* __restrict__ bias,           // b2l
    const unsigned short* __restrict__ Mw1,   // mw1 fragment-major
    const float* __restrict__ mb1,
    const float* __restrict__ mw2,
    const float* __restrict__ mb2,
    float* __restrict__ outf, int nrows) {
    __shared__ bfx8 ldsW[4096];               // 64 KB
    __shared__ unsigned short hlds[64 * HD];  // 16 KB

    int wid  = threadIdx.x >> 6;
    int lane = threadIdx.x & 63;
    int r  = lane & 15;
    int hi = lane >> 4;
    int ko = hi * 8;
    int row0 = blockIdx.x * 64 + wid * 16;

    int arow  = row0 + r;
    int arowc = min(arow, nrows - 1);

    bfx8 a[4], b[4];
    const unsigned short* Ar = A + (size_t)arowc * HD;
    const unsigned short* Br = B + (size_t)arowc * HD;
#pragma unroll
    for (int kk = 0; kk < 4; ++kk) {
        a[kk] = *(const bfx8*)(Ar + kk * 32 + ko);
        b[kk] = *(const bfx8*)(Br + kk * 32 + ko);
    }

    stage_lds(Wl, &ldsW[0],    32768);
    stage_lds(Wr, &ldsW[2048], 32768);

    float bv[8];
#pragma unroll
    for (int cf = 0; cf < 8; ++cf) bv[cf] = bias[cf * 16 + r];

    fx4 acc[8];
#pragma unroll
    for (int cf = 0; cf < 8; ++cf) acc[cf] = (fx4){0.f, 0.f, 0.f, 0.f};

    __syncthreads();

    // ---- stage 1: h2 = relu(A@Wl^T + B@Wr^T + b2) ----
#pragma unroll
    for (int kk = 0; kk < 4; ++kk) {
#pragma unroll
        for (int cf = 0; cf < 8; ++cf) {
            acc[cf] = __builtin_amdgcn_mfma_f32_16x16x32_bf16(
                a[kk], ldsW[(kk * 8 + cf) * 64 + lane], acc[cf], 0, 0, 0);
            acc[cf] = __builtin_amdgcn_mfma_f32_16x16x32_bf16(
                b[kk], ldsW[2048 + (kk * 8 + cf) * 64 + lane], acc[cf], 0, 0, 0);
        }
    }

#pragma unroll
    for (int cf = 0; cf < 8; ++cf) {
#pragma unroll
        for (int j = 0; j < 4; ++j) {
            int row_l = wid * 16 + hi * 4 + j;        // 0..63 block-local
            unsigned boff = (unsigned)(row_l * 256 + (cf * 16 + r) * 2);
            boff ^= (unsigned)((row_l & 7) << 4);
            *(unsigned short*)((char*)hlds + boff) = f2bf(fmaxf(acc[cf][j] + bv[cf], 0.f));
        }
    }
    __syncthreads();   // all stage-1 LDS reads done; hlds complete

    // reload Mw1 over the Wl region (safe: every wave is past the barrier)
    stage_lds(Mw1, &ldsW[0], 32768);

    // h2 A-frags from hlds (independent of the staging above)
    bfx8 af[4];
    {
        int row_l = wid * 16 + r;
#pragma unroll
        for (int kk = 0; kk < 4; ++kk) {
            unsigned boff = (unsigned)(row_l * 256 + (kk * 32 + ko) * 2);
            boff ^= (unsigned)((row_l & 7) << 4);
            af[kk] = *(const bfx8*)((char*)hlds + boff);
        }
    }

    float m1v[8], m2v[8];
#pragma unroll
    for (int cf = 0; cf < 8; ++cf) {
        m1v[cf] = mb1[cf * 16 + r];
        m2v[cf] = mw2[cf * 16 + r];
    }

    fx4 acc2[8];
#pragma unroll
    for (int cf = 0; cf < 8; ++cf) acc2[cf] = (fx4){0.f, 0.f, 0.f, 0.f};

    __syncthreads();   // drains Mw1 staging

#pragma unroll
    for (int kk = 0; kk < 4; ++kk) {
#pragma unroll
        for (int cf = 0; cf < 8; ++cf)
            acc2[cf] = __builtin_amdgcn_mfma_f32_16x16x32_bf16(
                af[kk], ldsW[(kk * 8 + cf) * 64 + lane], acc2[cf], 0, 0, 0);
    }

    float pd[4] = {0.f, 0.f, 0.f, 0.f};
#pragma unroll
    for (int cf = 0; cf < 8; ++cf) {
#pragma unroll
        for (int j = 0; j < 4; ++j)
            pd[j] += fmaxf(acc2[cf][j] + m1v[cf], 0.f) * m2v[cf];
    }

#pragma unroll
    for (int s = 1; s < 16; s <<= 1) {
#pragma unroll
        for (int j = 0; j < 4; ++j)
            pd[j] += __shfl_xor(pd[j], s, 64);
    }
    if (r == 0) {
        float mb = mb2[0];
#pragma unroll
        for (int j = 0; j < 4; ++j) {
            int row = row0 + hi * 4 + j;
            if (row < nrows) outf[row] = pd[j] + mb;
        }
    }
}

// ---------------- launch ----------------

extern "C" void kernel_launch(void* const* d_in, const int* in_sizes, int n_in,
                              void* d_out, int out_size, void* d_ws, size_t ws_size,
                              hipStream_t stream) {
    const float* x   = (const float*)d_in[0];
    const int*   ei  = (const int*)d_in[1];   // [2,E] int32
    const float* w1l = (const float*)d_in[2];
    const float* b1l = (const float*)d_in[3];
    const float* w1r = (const float*)d_in[4];
    const float* w2l = (const float*)d_in[5];
    const float* b2l = (const float*)d_in[6];
    const float* w2r = (const float*)d_in[7];
    const float* mw1 = (const float*)d_in[8];
    const float* mb1 = (const float*)d_in[9];
    const float* mw2 = (const float*)d_in[10];
    const float* mb2 = (const float*)d_in[11];
    float* out = (float*)d_out;

    const int N = in_sizes[0] / HD;   // 50000
    const int E = in_sizes[1] / 2;    // 1600000
    const int NBK = (N + BKSZ - 1) / BKSZ;   // 196

    char* p = (char*)d_ws;
    auto alloc = [&](size_t bytes) -> char* {
        char* q = p;
        p += (bytes + 255) & ~(size_t)255;
        return q;
    };
    int*            bcnt    = (int*)alloc((size_t)NBK * 4);
    int*            boff    = (int*)alloc(((size_t)NBK + 1) * 4);
    int*            offsets = (int*)alloc(((size_t)N + 1) * 4);
    int*            bpack   = (int*)alloc((size_t)NBK * BCAP * 4);
    int*            sorted  = (int*)alloc((size_t)E * 4);
    unsigned short* Wtb     = (unsigned short*)alloc((size_t)5 * HD * HD * 2);
    unsigned short* xb      = (unsigned short*)alloc((size_t)N * HD * 2);
    unsigned short* bufA    = (unsigned short*)alloc((size_t)N * HD * 2);
    unsigned short* bufB    = (unsigned short*)alloc((size_t)N * HD * 2);

    const unsigned short* W1l = Wtb + 0 * HD * HD;
    const unsigned short* W1r = Wtb + 1 * HD * HD;
    const unsigned short* W2l = Wtb + 2 * HD * HD;
    const unsigned short* W2r = Wtb + 3 * HD * HD;
    const unsigned short* Mw1 = Wtb + 4 * HD * HD;

    const int eb4k = (E + 4095) / 4096;    // 391
    const int gb   = (N + 63) / 64;        // 782
    const int ab   = (N + 3) / 4;          // 12500

    // CSR build (bucketed, packed, low-atomic)
    k_zero<<<1, 256, 0, stream>>>(bcnt, NBK);
    k_bin<<<eb4k, 256, 0, stream>>>(ei, E, NBK, bcnt, bpack);
    k_bscan<<<1, 1024, 0, stream>>>(bcnt, boff, NBK, E);
    k_bucket<<<NBK, 256, 0, stream>>>(bpack, bcnt, boff, offsets, sorted, N, E);

    // casts
    k_cast<<<(N * HD / 8 + 255) / 256, 256, 0, stream>>>(x, xb, N * HD / 8);
    k_cast5<<<40, 256, 0, stream>>>(w1l, w1r, w2l, w2r, mw1, Wtb);

    // layer 1
    k_aggr<<<ab, 256, 0, stream>>>(xb, offsets, sorted, bufA, N);
    k_gemm_mfma<<<gb, 256, 0, stream>>>(bufA, xb, W1l, W1r, b1l, bufB, N);
    // layer 2 aggr
    k_aggr<<<ab, 256, 0, stream>>>(bufB, offsets, sorted, bufA, N);
    // layer 2 GEMM + MLP + final, fused
    k_l2_fused<<<gb, 256, 0, stream>>>(bufA, bufB, W2l, W2r, b2l, Mw1, mb1, mw2, mb2,
                                       out, N);
}

// Round 12
// 258.179 us; speedup vs baseline: 1.0441x; 1.0441x over previous
//
#include <hip/hip_runtime.h>
#include <hip/hip_bf16.h>
#include <cstdint>

#define HD 128
#define BKSZ 256          // nodes per bucket
#define BCAP 12288        // bucket capacity (mean fill 8163, ~45 sigma headroom)

typedef __attribute__((ext_vector_type(8))) short bfx8;   // 8 bf16 in 4 VGPRs
typedef __attribute__((ext_vector_type(4))) float fx4;

__device__ inline float bf2f(short s) {
    union { uint32_t u; float f; } c;
    c.u = ((uint32_t)(unsigned short)s) << 16;
    return c.f;
}
__device__ inline unsigned short f2bf(float v) {
    union { float f; uint32_t u; } c;
    c.f = v;
    uint32_t u = c.u + 0x7FFF + ((c.u >> 16) & 1);   // RNE
    return (unsigned short)(u >> 16);
}

// async global->LDS staging: no VGPR destinations -> deep MLP regardless of
// register budget (m97 mechanism). Layout must be linear on both sides.
__device__ inline void stage_lds(const void* g, void* l, int nbytes) {
    const char* gc = (const char*)g;
    for (int off = threadIdx.x * 16; off < nbytes; off += 4096) {
        __builtin_amdgcn_global_load_lds(
            (const __attribute__((address_space(1))) unsigned int*)(gc + off),
            (__attribute__((address_space(3))) unsigned int*)
                ((__attribute__((address_space(3))) char*)l + off),
            16, 0, 0);
    }
}

__global__ void k_zero(int* __restrict__ p, int n) {
    for (int i = threadIdx.x; i < n; i += 256) p[i] = 0;
}

// ---------------- merged front-end: bin | cast | cast5 ----------------
// bucket b = dst >> 8 (256 nodes/bucket). Edge packed: (dst&255)<<24 | src.
// Block roles: [0, nbin) edge binning; [nbin, nbin+ncast) x cast;
// [nbin+ncast, +40) weight cast (fragment-major).

__global__ __launch_bounds__(256) void k_front(
    const int* __restrict__ ei, int E, int NBK,
    int* __restrict__ bcnt, int* __restrict__ bpack,
    const float* __restrict__ x, unsigned short* __restrict__ xb, int n8,
    const float* __restrict__ w0, const float* __restrict__ w1,
    const float* __restrict__ w2, const float* __restrict__ w3,
    const float* __restrict__ w4, unsigned short* __restrict__ wout,
    int nbin, int ncast) {
    __shared__ int lhist[BKSZ];
    __shared__ int gbase[BKSZ];

    int bid = blockIdx.x;
    if (bid < nbin) {
        // ---- edge binning (LDS-aggregated; one packed 4B write per edge) ----
        int base = bid * 4096;
        for (int i = threadIdx.x; i < NBK; i += 256) lhist[i] = 0;
        __syncthreads();

        int pw[16];
        int meta[16];
        const int4* s4 = (const int4*)ei;
        const int4* d4 = (const int4*)(ei + E);
        int c0 = base >> 2;
        int EC = E >> 2;                       // E % 4 == 0
#pragma unroll
        for (int j = 0; j < 4; ++j) {
            int c4 = c0 + j * 256 + threadIdx.x;
            bool ok = (c4 < EC);
            int4 sv = make_int4(0, 0, 0, 0), dv = make_int4(0, 0, 0, 0);
            if (ok) { sv = s4[c4]; dv = d4[c4]; }
            int ss[4] = {sv.x, sv.y, sv.z, sv.w};
            int dd[4] = {dv.x, dv.y, dv.z, dv.w};
#pragma unroll
            for (int l = 0; l < 4; ++l) {
                int idx = j * 4 + l;
                meta[idx] = -1;
                if (ok) {
                    int d = dd[l];
                    int b = d >> 8;
                    int lr = atomicAdd(&lhist[b], 1);          // LDS atomic
                    pw[idx]   = ((d & 255) << 24) | ss[l];
                    meta[idx] = (b << 16) | lr;                // b<=195, lr<4096
                }
            }
        }
        __syncthreads();
        for (int i = threadIdx.x; i < NBK; i += 256) {
            int c = lhist[i];
            gbase[i] = c ? atomicAdd(&bcnt[i], c) : 0;         // 1 global atomic/bucket
        }
        __syncthreads();
#pragma unroll
        for (int idx = 0; idx < 16; ++idx) {
            int m = meta[idx];
            if (m >= 0) {
                int b = m >> 16, lr = m & 0xFFFF;
                int pos = b * BCAP + min(gbase[b] + lr, BCAP - 1);  // clamp: no OOB
                bpack[pos] = pw[idx];
            }
        }
    } else if (bid < nbin + ncast) {
        // ---- x fp32 -> bf16 ----
        int i = (bid - nbin) * 256 + threadIdx.x;
        if (i >= n8) return;
        float4 v0 = ((const float4*)x)[i * 2];
        float4 v1 = ((const float4*)x)[i * 2 + 1];
        bfx8 o;
        o[0] = (short)f2bf(v0.x); o[1] = (short)f2bf(v0.y);
        o[2] = (short)f2bf(v0.z); o[3] = (short)f2bf(v0.w);
        o[4] = (short)f2bf(v1.x); o[5] = (short)f2bf(v1.y);
        o[6] = (short)f2bf(v1.z); o[7] = (short)f2bf(v1.w);
        *(bfx8*)(xb + (size_t)i * 8) = o;
    } else {
        // ---- five 128x128 weights -> bf16 FRAGMENT-MAJOR:
        // slot s=(kk*8+cf)*64+l holds W[cf*16+(l&15)][kk*32+(l>>4)*8 .. +7] ----
        int t = (bid - nbin - ncast) * 256 + threadIdx.x;   // 5 * 2048 slots
        if (t >= 5 * 2048) return;
        int m = t / 2048, s = t % 2048;
        const float* src = (m == 0) ? w0 : (m == 1) ? w1 : (m == 2) ? w2
                                                   : (m == 3) ? w3 : w4;
        int l  = s & 63;
        int fi = s >> 6;          // 0..31
        int kk = fi >> 3;
        int cf = fi & 7;
        int r  = l & 15;
        int hi = l >> 4;
        int row  = cf * 16 + r;
        int col0 = kk * 32 + hi * 8;
        const float4* sp = (const float4*)(src + row * HD + col0);   // 32B aligned
        float4 v0 = sp[0];
        float4 v1 = sp[1];
        bfx8 o;
        o[0] = (short)f2bf(v0.x); o[1] = (short)f2bf(v0.y);
        o[2] = (short)f2bf(v0.z); o[3] = (short)f2bf(v0.w);
        o[4] = (short)f2bf(v1.x); o[5] = (short)f2bf(v1.y);
        o[6] = (short)f2bf(v1.z); o[7] = (short)f2bf(v1.w);
        *(bfx8*)(wout + (size_t)t * 8) = o;
    }
}

// ---------------- per-bucket local sort (inline bcnt prefix, no bscan) ----------------
__global__ __launch_bounds__(256) void k_bucket(const int* __restrict__ bpack,
                                                const int* __restrict__ bcnt,
                                                int* __restrict__ offsets,
                                                int* __restrict__ sorted,
                                                int N, int E) {
    __shared__ int lh[BKSZ];
    __shared__ int cur[BKSZ];
    __shared__ int wsum[4];
    __shared__ int psum[4];
    int b = blockIdx.x;
    int tid = threadIdx.x;
    int lane = tid & 63;
    int wid = tid >> 6;

    // inline exclusive prefix of bcnt: obase = sum_{i<b} bcnt[i]  (b < 256)
    int pv = (tid < b) ? bcnt[tid] : 0;
    int ps = pv;
#pragma unroll
    for (int s = 1; s < 64; s <<= 1) ps += __shfl_xor(ps, s, 64);
    if (lane == 0) psum[wid] = ps;

    int cnt = min(bcnt[b], BCAP);
    int base = b * BCAP;
    lh[tid] = 0;
    __syncthreads();
    int obase = psum[0] + psum[1] + psum[2] + psum[3];

    for (int i = tid; i < cnt; i += 256)
        atomicAdd(&lh[((unsigned)bpack[base + i]) >> 24], 1);
    __syncthreads();

    // 256-entry exclusive scan: intra-wave shfl + cross-wave prefix
    int v = lh[tid];
    int sum = v;
#pragma unroll
    for (int s = 1; s < 64; s <<= 1) {
        int o = __shfl_up(sum, s, 64);
        if ((tid & 63) >= s) sum += o;
    }
    if ((tid & 63) == 63) wsum[wid] = sum;
    __syncthreads();
    int prefix = 0;
#pragma unroll
    for (int w = 0; w < 4; ++w)
        if (w < wid) prefix += wsum[w];
    int excl = prefix + sum - v;
    int n = b * BKSZ + tid;
    if (n < N) offsets[n] = obase + excl;
    cur[tid] = excl;
    __syncthreads();

    for (int i = tid; i < cnt; i += 256) {
        int w = bpack[base + i];
        int ln = ((unsigned)w) >> 24;
        int p = atomicAdd(&cur[ln], 1);          // LDS atomic
        sorted[obase + p] = w & 0xFFFFFF;
    }
    if (b == 0 && tid == 0) offsets[N] = E;
}

// ---------------- mean aggregation: one wave per node, shfl reduce ----------------
// (R10-proven version: interleaved stride-4 slots, 2-deep.)

__global__ __launch_bounds__(256) void k_aggr(const unsigned short* __restrict__ x,
                                              const int* __restrict__ offsets,
                                              const int* __restrict__ sorted_src,
                                              unsigned short* __restrict__ out, int N) {
    int wid  = threadIdx.x >> 6;
    int lane = threadIdx.x & 63;
    int n = blockIdx.x * 4 + wid;
    if (n >= N) return;
    int slot = lane >> 4;     // 0..3
    int c    = lane & 15;     // feature octet
    int beg = offsets[n], end = offsets[n + 1];

    float acc[8];
#pragma unroll
    for (int j = 0; j < 8; ++j) acc[j] = 0.f;

    int e = beg + slot;
    for (; e + 4 < end; e += 8) {
        int i0 = sorted_src[e];
        int i1 = sorted_src[e + 4];
        bfx8 v0 = *(const bfx8*)(x + (size_t)i0 * HD + c * 8);
        bfx8 v1 = *(const bfx8*)(x + (size_t)i1 * HD + c * 8);
#pragma unroll
        for (int j = 0; j < 8; ++j) acc[j] += bf2f(v0[j]);
#pragma unroll
        for (int j = 0; j < 8; ++j) acc[j] += bf2f(v1[j]);
    }
    if (e < end) {
        int i0 = sorted_src[e];
        bfx8 v0 = *(const bfx8*)(x + (size_t)i0 * HD + c * 8);
#pragma unroll
        for (int j = 0; j < 8; ++j) acc[j] += bf2f(v0[j]);
    }

#pragma unroll
    for (int j = 0; j < 8; ++j) {
        acc[j] += __shfl_xor(acc[j], 16, 64);
        acc[j] += __shfl_xor(acc[j], 32, 64);
    }
    if (slot == 0) {
        float inv = 1.f / fmaxf((float)(end - beg), 1.f);
        bfx8 o;
#pragma unroll
        for (int j = 0; j < 8; ++j) o[j] = (short)f2bf(acc[j] * inv);
        *(bfx8*)(out + (size_t)n * HD + c * 8) = o;
    }
}

// ---------------- layer-1 MFMA dual GEMM (LDS-staged weights) ----------------
// Wl+Wr (64KB, fragment-major) staged to LDS via global_load_lds once/block;
// all 4 waves share them. Weight ds_read_b128 is stride-1 (conflict-free).
// mfma_f32_16x16x32_bf16: A lane: row=l&15, k=(l>>4)*8+j ; B lane: col=l&15 ;
// D: col=l&15, row=(l>>4)*4+reg  [m89-verified].

__global__ __launch_bounds__(256) void k_gemm_mfma(
    const unsigned short* __restrict__ A,
    const unsigned short* __restrict__ B,
    const unsigned short* __restrict__ Wl,   // fragment-major
    const unsigned short* __restrict__ Wr,   // fragment-major
    const float* __restrict__ bias,
    unsigned short* __restrict__ outb, int nrows) {
    __shared__ bfx8 ldsW[4096];              // 64 KB: [0..2048)=Wl, [2048..4096)=Wr

    int wid  = threadIdx.x >> 6;
    int lane = threadIdx.x & 63;
    int r  = lane & 15;
    int hi = lane >> 4;          // 0..3
    int ko = hi * 8;
    int row0 = blockIdx.x * 64 + wid * 16;

    int arow  = row0 + r;
    int arowc = min(arow, nrows - 1);

    // issue per-lane A/B row loads first (latency overlaps the staging)
    bfx8 a[4], b[4];
    const unsigned short* Ar = A + (size_t)arowc * HD;
    const unsigned short* Br = B + (size_t)arowc * HD;
#pragma unroll
    for (int kk = 0; kk < 4; ++kk) {
        a[kk] = *(const bfx8*)(Ar + kk * 32 + ko);
        b[kk] = *(const bfx8*)(Br + kk * 32 + ko);
    }

    stage_lds(Wl, &ldsW[0],    32768);
    stage_lds(Wr, &ldsW[2048], 32768);

    float bv[8];
#pragma unroll
    for (int cf = 0; cf < 8; ++cf) bv[cf] = bias[cf * 16 + r];

    fx4 acc[8];
#pragma unroll
    for (int cf = 0; cf < 8; ++cf) acc[cf] = (fx4){0.f, 0.f, 0.f, 0.f};

    __syncthreads();   // drains global_load_lds (vmcnt) + all waves see LDS

#pragma unroll
    for (int kk = 0; kk < 4; ++kk) {
#pragma unroll
        for (int cf = 0; cf < 8; ++cf) {
            acc[cf] = __builtin_amdgcn_mfma_f32_16x16x32_bf16(
                a[kk], ldsW[(kk * 8 + cf) * 64 + lane], acc[cf], 0, 0, 0);
            acc[cf] = __builtin_amdgcn_mfma_f32_16x16x32_bf16(
                b[kk], ldsW[2048 + (kk * 8 + cf) * 64 + lane], acc[cf], 0, 0, 0);
        }
    }

#pragma unroll
    for (int cf = 0; cf < 8; ++cf) {
#pragma unroll
        for (int j = 0; j < 4; ++j) {
            int row = row0 + hi * 4 + j;
            if (row < nrows)
                outb[(size_t)row * HD + cf * 16 + r] = f2bf(fmaxf(acc[cf][j] + bv[cf], 0.f));
        }
    }
}

// ---------------- fused layer2 + MLP + final dot (LDS-staged weights) ----------------
// Stage W2l+W2r -> compute h2 -> hlds; reload Mw1 into same LDS; stage-2 GEMM
// + fused mw2 dot. hlds swizzle: byte ^= (row&7)<<4 (stride-256B column reads).

__global__ __launch_bounds__(256) void k_l2_fused(
    const unsigned short* __restrict__ A,     // aggr2
    const unsigned short* __restrict__ B,     // h1
    const unsigned short* __restrict__ Wl,    // w2l fragment-major
    const unsigned short* __restrict__ Wr,    // w2r fragment-major
    const float* __restrict__ bias,           // b2l
    const unsigned short* __restrict__ Mw1,   // mw1 fragment-major
    const float* __restrict__ mb1,
    const float* __restrict__ mw2,
    const float* __restrict__ mb2,
    float* __restrict__ outf, int nrows) {
    __shared__ bfx8 ldsW[4096];               // 64 KB
    __shared__ unsigned short hlds[64 * HD];  // 16 KB

    int wid  = threadIdx.x >> 6;
    int lane = threadIdx.x & 63;
    int r  = lane & 15;
    int hi = lane >> 4;
    int ko = hi * 8;
    int row0 = blockIdx.x * 64 + wid * 16;

    int arow  = row0 + r;
    int arowc = min(arow, nrows - 1);

    bfx8 a[4], b[4];
    const unsigned short* Ar = A + (size_t)arowc * HD;
    const unsigned short* Br = B + (size_t)arowc * HD;
#pragma unroll
    for (int kk = 0; kk < 4; ++kk) {
        a[kk] = *(const bfx8*)(Ar + kk * 32 + ko);
        b[kk] = *(const bfx8*)(Br + kk * 32 + ko);
    }

    stage_lds(Wl, &ldsW[0],    32768);
    stage_lds(Wr, &ldsW[2048], 32768);

    float bv[8];
#pragma unroll
    for (int cf = 0; cf < 8; ++cf) bv[cf] = bias[cf * 16 + r];

    fx4 acc[8];
#pragma unroll
    for (int cf = 0; cf < 8; ++cf) acc[cf] = (fx4){0.f, 0.f, 0.f, 0.f};

    __syncthreads();

    // ---- stage 1: h2 = relu(A@Wl^T + B@Wr^T + b2) ----
#pragma unroll
    for (int kk = 0; kk < 4; ++kk) {
#pragma unroll
        for (int cf = 0; cf < 8; ++cf) {
            acc[cf] = __builtin_amdgcn_mfma_f32_16x16x32_bf16(
                a[kk], ldsW[(kk * 8 + cf) * 64 + lane], acc[cf], 0, 0, 0);
            acc[cf] = __builtin_amdgcn_mfma_f32_16x16x32_bf16(
                b[kk], ldsW[2048 + (kk * 8 + cf) * 64 + lane], acc[cf], 0, 0, 0);
        }
    }

#pragma unroll
    for (int cf = 0; cf < 8; ++cf) {
#pragma unroll
        for (int j = 0; j < 4; ++j) {
            int row_l = wid * 16 + hi * 4 + j;        // 0..63 block-local
            unsigned boff = (unsigned)(row_l * 256 + (cf * 16 + r) * 2);
            boff ^= (unsigned)((row_l & 7) << 4);
            *(unsigned short*)((char*)hlds + boff) = f2bf(fmaxf(acc[cf][j] + bv[cf], 0.f));
        }
    }
    __syncthreads();   // all stage-1 LDS reads done; hlds complete

    // reload Mw1 over the Wl region (safe: every wave is past the barrier)
    stage_lds(Mw1, &ldsW[0], 32768);

    // h2 A-frags from hlds (independent of the staging above)
    bfx8 af[4];
    {
        int row_l = wid * 16 + r;
#pragma unroll
        for (int kk = 0; kk < 4; ++kk) {
            unsigned boff = (unsigned)(row_l * 256 + (kk * 32 + ko) * 2);
            boff ^= (unsigned)((row_l & 7) << 4);
            af[kk] = *(const bfx8*)((char*)hlds + boff);
        }
    }

    float m1v[8], m2v[8];
#pragma unroll
    for (int cf = 0; cf < 8; ++cf) {
        m1v[cf] = mb1[cf * 16 + r];
        m2v[cf] = mw2[cf * 16 + r];
    }

    fx4 acc2[8];
#pragma unroll
    for (int cf = 0; cf < 8; ++cf) acc2[cf] = (fx4){0.f, 0.f, 0.f, 0.f};

    __syncthreads();   // drains Mw1 staging

#pragma unroll
    for (int kk = 0; kk < 4; ++kk) {
#pragma unroll
        for (int cf = 0; cf < 8; ++cf)
            acc2[cf] = __builtin_amdgcn_mfma_f32_16x16x32_bf16(
                af[kk], ldsW[(kk * 8 + cf) * 64 + lane], acc2[cf], 0, 0, 0);
    }

    float pd[4] = {0.f, 0.f, 0.f, 0.f};
#pragma unroll
    for (int cf = 0; cf < 8; ++cf) {
#pragma unroll
        for (int j = 0; j < 4; ++j)
            pd[j] += fmaxf(acc2[cf][j] + m1v[cf], 0.f) * m2v[cf];
    }

#pragma unroll
    for (int s = 1; s < 16; s <<= 1) {
#pragma unroll
        for (int j = 0; j < 4; ++j)
            pd[j] += __shfl_xor(pd[j], s, 64);
    }
    if (r == 0) {
        float mb = mb2[0];
#pragma unroll
        for (int j = 0; j < 4; ++j) {
            int row = row0 + hi * 4 + j;
            if (row < nrows) outf[row] = pd[j] + mb;
        }
    }
}

// ---------------- launch ----------------

extern "C" void kernel_launch(void* const* d_in, const int* in_sizes, int n_in,
                              void* d_out, int out_size, void* d_ws, size_t ws_size,
                              hipStream_t stream) {
    const float* x   = (const float*)d_in[0];
    const int*   ei  = (const int*)d_in[1];   // [2,E] int32
    const float* w1l = (const float*)d_in[2];
    const float* b1l = (const float*)d_in[3];
    const float* w1r = (const float*)d_in[4];
    const float* w2l = (const float*)d_in[5];
    const float* b2l = (const float*)d_in[6];
    const float* w2r = (const float*)d_in[7];
    const float* mw1 = (const float*)d_in[8];
    const float* mb1 = (const float*)d_in[9];
    const float* mw2 = (const float*)d_in[10];
    const float* mb2 = (const float*)d_in[11];
    float* out = (float*)d_out;

    const int N = in_sizes[0] / HD;   // 50000
    const int E = in_sizes[1] / 2;    // 1600000
    const int NBK = (N + BKSZ - 1) / BKSZ;   // 196
    const int n8 = N * HD / 8;               // 800000

    char* p = (char*)d_ws;
    auto alloc = [&](size_t bytes) -> char* {
        char* q = p;
        p += (bytes + 255) & ~(size_t)255;
        return q;
    };
    int*            bcnt    = (int*)alloc((size_t)NBK * 4);
    int*            offsets = (int*)alloc(((size_t)N + 1) * 4);
    int*            bpack   = (int*)alloc((size_t)NBK * BCAP * 4);
    int*            sorted  = (int*)alloc((size_t)E * 4);
    unsigned short* Wtb     = (unsigned short*)alloc((size_t)5 * HD * HD * 2);
    unsigned short* xb      = (unsigned short*)alloc((size_t)N * HD * 2);
    unsigned short* bufA    = (unsigned short*)alloc((size_t)N * HD * 2);
    unsigned short* bufB    = (unsigned short*)alloc((size_t)N * HD * 2);

    const unsigned short* W1l = Wtb + 0 * HD * HD;
    const unsigned short* W1r = Wtb + 1 * HD * HD;
    const unsigned short* W2l = Wtb + 2 * HD * HD;
    const unsigned short* W2r = Wtb + 3 * HD * HD;
    const unsigned short* Mw1 = Wtb + 4 * HD * HD;

    const int nbin  = (E + 4095) / 4096;     // 391
    const int ncast = (n8 + 255) / 256;      // 3125
    const int nc5   = 40;
    const int gb    = (N + 63) / 64;         // 782
    const int ab    = (N + 3) / 4;           // 12500

    // 7-launch pipeline
    k_zero<<<1, 256, 0, stream>>>(bcnt, NBK);
    k_front<<<nbin + ncast + nc5, 256, 0, stream>>>(
        ei, E, NBK, bcnt, bpack, x, xb, n8,
        w1l, w1r, w2l, w2r, mw1, Wtb, nbin, ncast);
    k_bucket<<<NBK, 256, 0, stream>>>(bpack, bcnt, offsets, sorted, N, E);

    // layer 1
    k_aggr<<<ab, 256, 0, stream>>>(xb, offsets, sorted, bufA, N);
    k_gemm_mfma<<<gb, 256, 0, stream>>>(bufA, xb, W1l, W1r, b1l, bufB, N);
    // layer 2 aggr
    k_aggr<<<ab, 256, 0, stream>>>(bufB, offsets, sorted, bufA, N);
    // layer 2 GEMM + MLP + final, fused
    k_l2_fused<<<gb, 256, 0, stream>>>(bufA, bufB, W2l, W2r, b2l, Mw1, mb1, mw2, mb2,
                                       out, N);
}

// Round 13
// 252.347 us; speedup vs baseline: 1.0683x; 1.0231x over previous
//
#include <hip/hip_runtime.h>
#include <hip/hip_bf16.h>
#include <cstdint>

#define HD 128
#define BKSZ 256          // nodes per bucket
#define BCAP 12288        // bucket capacity (mean fill 8163, ~45 sigma headroom)
#define EBIN 2048         // edges per bin block (3 blocks/CU)

typedef __attribute__((ext_vector_type(8))) short bfx8;   // 8 bf16 in 4 VGPRs
typedef __attribute__((ext_vector_type(4))) float fx4;

__device__ inline float bf2f(short s) {
    union { uint32_t u; float f; } c;
    c.u = ((uint32_t)(unsigned short)s) << 16;
    return c.f;
}
__device__ inline unsigned short f2bf(float v) {
    union { float f; uint32_t u; } c;
    c.f = v;
    uint32_t u = c.u + 0x7FFF + ((c.u >> 16) & 1);   // RNE
    return (unsigned short)(u >> 16);
}

// async global->LDS staging: no VGPR destinations -> deep MLP regardless of
// register budget (m97 mechanism). Layout must be linear on both sides.
__device__ inline void stage_lds(const void* g, void* l, int nbytes) {
    const char* gc = (const char*)g;
    for (int off = threadIdx.x * 16; off < nbytes; off += 4096) {
        __builtin_amdgcn_global_load_lds(
            (const __attribute__((address_space(1))) unsigned int*)(gc + off),
            (__attribute__((address_space(3))) unsigned int*)
                ((__attribute__((address_space(3))) char*)l + off),
            16, 0, 0);
    }
}

__global__ void k_zero(int* __restrict__ p, int n) {
    for (int i = threadIdx.x; i < n; i += 256) p[i] = 0;
}

// ---------------- merged front-end: bin | cast | cast5 ----------------
// bucket b = dst >> 8 (256 nodes/bucket). Edge packed: (dst&255)<<24 | src.
// Block roles: [0, nbin) edge binning (EBIN edges each); [nbin, nbin+ncast)
// x cast; [nbin+ncast, +40) weight cast (fragment-major).

__global__ __launch_bounds__(256) void k_front(
    const int* __restrict__ ei, int E, int NBK,
    int* __restrict__ bcnt, int* __restrict__ bpack,
    const float* __restrict__ x, unsigned short* __restrict__ xb, int n8,
    const float* __restrict__ w0, const float* __restrict__ w1,
    const float* __restrict__ w2, const float* __restrict__ w3,
    const float* __restrict__ w4, unsigned short* __restrict__ wout,
    int nbin, int ncast) {
    __shared__ int lhist[BKSZ];
    __shared__ int gbase[BKSZ];

    int bid = blockIdx.x;
    if (bid < nbin) {
        // ---- edge binning (LDS-aggregated; one packed 4B write per edge) ----
        int base = bid * EBIN;
        for (int i = threadIdx.x; i < NBK; i += 256) lhist[i] = 0;
        __syncthreads();

        int pw[8];
        int meta[8];
        const int4* s4 = (const int4*)ei;
        const int4* d4 = (const int4*)(ei + E);
        int c0 = base >> 2;
        int EC = E >> 2;                       // E % 4 == 0
#pragma unroll
        for (int j = 0; j < 2; ++j) {
            int c4 = c0 + j * 256 + threadIdx.x;
            bool ok = (c4 < EC);
            int4 sv = make_int4(0, 0, 0, 0), dv = make_int4(0, 0, 0, 0);
            if (ok) { sv = s4[c4]; dv = d4[c4]; }
            int ss[4] = {sv.x, sv.y, sv.z, sv.w};
            int dd[4] = {dv.x, dv.y, dv.z, dv.w};
#pragma unroll
            for (int l = 0; l < 4; ++l) {
                int idx = j * 4 + l;
                meta[idx] = -1;
                if (ok) {
                    int d = dd[l];
                    int b = d >> 8;
                    int lr = atomicAdd(&lhist[b], 1);          // LDS atomic
                    pw[idx]   = ((d & 255) << 24) | ss[l];
                    meta[idx] = (b << 16) | lr;                // b<=195, lr<2048
                }
            }
        }
        __syncthreads();
        for (int i = threadIdx.x; i < NBK; i += 256) {
            int c = lhist[i];
            gbase[i] = c ? atomicAdd(&bcnt[i], c) : 0;         // 1 global atomic/bucket
        }
        __syncthreads();
#pragma unroll
        for (int idx = 0; idx < 8; ++idx) {
            int m = meta[idx];
            if (m >= 0) {
                int b = m >> 16, lr = m & 0xFFFF;
                int pos = b * BCAP + min(gbase[b] + lr, BCAP - 1);  // clamp: no OOB
                bpack[pos] = pw[idx];
            }
        }
    } else if (bid < nbin + ncast) {
        // ---- x fp32 -> bf16 ----
        int i = (bid - nbin) * 256 + threadIdx.x;
        if (i >= n8) return;
        float4 v0 = ((const float4*)x)[i * 2];
        float4 v1 = ((const float4*)x)[i * 2 + 1];
        bfx8 o;
        o[0] = (short)f2bf(v0.x); o[1] = (short)f2bf(v0.y);
        o[2] = (short)f2bf(v0.z); o[3] = (short)f2bf(v0.w);
        o[4] = (short)f2bf(v1.x); o[5] = (short)f2bf(v1.y);
        o[6] = (short)f2bf(v1.z); o[7] = (short)f2bf(v1.w);
        *(bfx8*)(xb + (size_t)i * 8) = o;
    } else {
        // ---- five 128x128 weights -> bf16 FRAGMENT-MAJOR:
        // slot s=(kk*8+cf)*64+l holds W[cf*16+(l&15)][kk*32+(l>>4)*8 .. +7] ----
        int t = (bid - nbin - ncast) * 256 + threadIdx.x;   // 5 * 2048 slots
        if (t >= 5 * 2048) return;
        int m = t / 2048, s = t % 2048;
        const float* src = (m == 0) ? w0 : (m == 1) ? w1 : (m == 2) ? w2
                                                   : (m == 3) ? w3 : w4;
        int l  = s & 63;
        int fi = s >> 6;          // 0..31
        int kk = fi >> 3;
        int cf = fi & 7;
        int r  = l & 15;
        int hi = l >> 4;
        int row  = cf * 16 + r;
        int col0 = kk * 32 + hi * 8;
        const float4* sp = (const float4*)(src + row * HD + col0);   // 32B aligned
        float4 v0 = sp[0];
        float4 v1 = sp[1];
        bfx8 o;
        o[0] = (short)f2bf(v0.x); o[1] = (short)f2bf(v0.y);
        o[2] = (short)f2bf(v0.z); o[3] = (short)f2bf(v0.w);
        o[4] = (short)f2bf(v1.x); o[5] = (short)f2bf(v1.y);
        o[6] = (short)f2bf(v1.z); o[7] = (short)f2bf(v1.w);
        *(bfx8*)(wout + (size_t)t * 8) = o;
    }
}

// ---------------- per-bucket local sort (512 threads, inline prefix) ----------------
__global__ __launch_bounds__(512) void k_bucket(const int* __restrict__ bpack,
                                                const int* __restrict__ bcnt,
                                                int* __restrict__ offsets,
                                                int* __restrict__ sorted,
                                                int N, int E) {
    __shared__ int lh[BKSZ];
    __shared__ int cur[BKSZ];
    __shared__ int wsum[4];
    __shared__ int psum[8];
    int b = blockIdx.x;
    int tid = threadIdx.x;
    int lane = tid & 63;
    int wid = tid >> 6;          // 0..7

    // inline exclusive prefix of bcnt: obase = sum_{i<b} bcnt[i]  (b < 256)
    int pv = (tid < b) ? bcnt[tid] : 0;
    int ps = pv;
#pragma unroll
    for (int s = 1; s < 64; s <<= 1) ps += __shfl_xor(ps, s, 64);
    if (lane == 0) psum[wid] = ps;

    int cnt = min(bcnt[b], BCAP);
    int base = b * BCAP;
    if (tid < BKSZ) lh[tid] = 0;
    __syncthreads();
    int obase = psum[0] + psum[1] + psum[2] + psum[3]
              + psum[4] + psum[5] + psum[6] + psum[7];

    for (int i = tid; i < cnt; i += 512)
        atomicAdd(&lh[((unsigned)bpack[base + i]) >> 24], 1);
    __syncthreads();

    // 256-entry exclusive scan over lh: waves 0-3 only
    if (tid < BKSZ) {
        int v = lh[tid];
        int sum = v;
#pragma unroll
        for (int s = 1; s < 64; s <<= 1) {
            int o = __shfl_up(sum, s, 64);
            if ((tid & 63) >= s) sum += o;
        }
        if ((tid & 63) == 63) wsum[wid] = sum;
        __syncthreads();
        int prefix = 0;
#pragma unroll
        for (int w = 0; w < 4; ++w)
            if (w < wid) prefix += wsum[w];
        int excl = prefix + sum - v;
        int n = b * BKSZ + tid;
        if (n < N) offsets[n] = obase + excl;
        cur[tid] = excl;
    } else {
        __syncthreads();
    }
    __syncthreads();

    for (int i = tid; i < cnt; i += 512) {
        int w = bpack[base + i];
        int ln = ((unsigned)w) >> 24;
        int p = atomicAdd(&cur[ln], 1);          // LDS atomic
        sorted[obase + p] = w & 0xFFFFFF;
    }
    if (b == 0 && tid == 0) offsets[N] = E;
}

// ---------------- mean aggregation: one wave per node, shfl reduce ----------------
// (R10-proven version: interleaved stride-4 slots, 2-deep.)

__global__ __launch_bounds__(256) void k_aggr(const unsigned short* __restrict__ x,
                                              const int* __restrict__ offsets,
                                              const int* __restrict__ sorted_src,
                                              unsigned short* __restrict__ out, int N) {
    int wid  = threadIdx.x >> 6;
    int lane = threadIdx.x & 63;
    int n = blockIdx.x * 4 + wid;
    if (n >= N) return;
    int slot = lane >> 4;     // 0..3
    int c    = lane & 15;     // feature octet
    int beg = offsets[n], end = offsets[n + 1];

    float acc[8];
#pragma unroll
    for (int j = 0; j < 8; ++j) acc[j] = 0.f;

    int e = beg + slot;
    for (; e + 4 < end; e += 8) {
        int i0 = sorted_src[e];
        int i1 = sorted_src[e + 4];
        bfx8 v0 = *(const bfx8*)(x + (size_t)i0 * HD + c * 8);
        bfx8 v1 = *(const bfx8*)(x + (size_t)i1 * HD + c * 8);
#pragma unroll
        for (int j = 0; j < 8; ++j) acc[j] += bf2f(v0[j]);
#pragma unroll
        for (int j = 0; j < 8; ++j) acc[j] += bf2f(v1[j]);
    }
    if (e < end) {
        int i0 = sorted_src[e];
        bfx8 v0 = *(const bfx8*)(x + (size_t)i0 * HD + c * 8);
#pragma unroll
        for (int j = 0; j < 8; ++j) acc[j] += bf2f(v0[j]);
    }

#pragma unroll
    for (int j = 0; j < 8; ++j) {
        acc[j] += __shfl_xor(acc[j], 16, 64);
        acc[j] += __shfl_xor(acc[j], 32, 64);
    }
    if (slot == 0) {
        float inv = 1.f / fmaxf((float)(end - beg), 1.f);
        bfx8 o;
#pragma unroll
        for (int j = 0; j < 8; ++j) o[j] = (short)f2bf(acc[j] * inv);
        *(bfx8*)(out + (size_t)n * HD + c * 8) = o;
    }
}

// ---------------- layer-1 MFMA dual GEMM (LDS-staged weights) ----------------
// Wl+Wr (64KB, fragment-major) staged to LDS via global_load_lds once/block;
// all 4 waves share them. Weight ds_read_b128 is stride-1 (conflict-free).
// mfma_f32_16x16x32_bf16: A lane: row=l&15, k=(l>>4)*8+j ; B lane: col=l&15 ;
// D: col=l&15, row=(l>>4)*4+reg  [m89-verified].

__global__ __launch_bounds__(256) void k_gemm_mfma(
    const unsigned short* __restrict__ A,
    const unsigned short* __restrict__ B,
    const unsigned short* __restrict__ Wl,   // fragment-major
    const unsigned short* __restrict__ Wr,   // fragment-major
    const float* __restrict__ bias,
    unsigned short* __restrict__ outb, int nrows) {
    __shared__ bfx8 ldsW[4096];              // 64 KB: [0..2048)=Wl, [2048..4096)=Wr

    int wid  = threadIdx.x >> 6;
    int lane = threadIdx.x & 63;
    int r  = lane & 15;
    int hi = lane >> 4;          // 0..3
    int ko = hi * 8;
    int row0 = blockIdx.x * 64 + wid * 16;

    int arow  = row0 + r;
    int arowc = min(arow, nrows - 1);

    // issue per-lane A/B row loads first (latency overlaps the staging)
    bfx8 a[4], b[4];
    const unsigned short* Ar = A + (size_t)arowc * HD;
    const unsigned short* Br = B + (size_t)arowc * HD;
#pragma unroll
    for (int kk = 0; kk < 4; ++kk) {
        a[kk] = *(const bfx8*)(Ar + kk * 32 + ko);
        b[kk] = *(const bfx8*)(Br + kk * 32 + ko);
    }

    stage_lds(Wl, &ldsW[0],    32768);
    stage_lds(Wr, &ldsW[2048], 32768);

    float bv[8];
#pragma unroll
    for (int cf = 0; cf < 8; ++cf) bv[cf] = bias[cf * 16 + r];

    fx4 acc[8];
#pragma unroll
    for (int cf = 0; cf < 8; ++cf) acc[cf] = (fx4){0.f, 0.f, 0.f, 0.f};

    __syncthreads();   // drains global_load_lds (vmcnt) + all waves see LDS

#pragma unroll
    for (int kk = 0; kk < 4; ++kk) {
#pragma unroll
        for (int cf = 0; cf < 8; ++cf) {
            acc[cf] = __builtin_amdgcn_mfma_f32_16x16x32_bf16(
                a[kk], ldsW[(kk * 8 + cf) * 64 + lane], acc[cf], 0, 0, 0);
            acc[cf] = __builtin_amdgcn_mfma_f32_16x16x32_bf16(
                b[kk], ldsW[2048 + (kk * 8 + cf) * 64 + lane], acc[cf], 0, 0, 0);
        }
    }

#pragma unroll
    for (int cf = 0; cf < 8; ++cf) {
#pragma unroll
        for (int j = 0; j < 4; ++j) {
            int row = row0 + hi * 4 + j;
            if (row < nrows)
                outb[(size_t)row * HD + cf * 16 + r] = f2bf(fmaxf(acc[cf][j] + bv[cf], 0.f));
        }
    }
}

// ---------------- fused layer2 + MLP + final dot (LDS-staged weights) ----------------
// Stage W2l+W2r -> compute h2 -> hlds; reload Mw1 into same LDS; stage-2 GEMM
// + fused mw2 dot. hlds swizzle: byte ^= (row&7)<<4 (stride-256B column reads).

__global__ __launch_bounds__(256) void k_l2_fused(
    const unsigned short* __restrict__ A,     // aggr2
    const unsigned short* __restrict__ B,     // h1
    const unsigned short* __restrict__ Wl,    // w2l fragment-major
    const unsigned short* __restrict__ Wr,    // w2r fragment-major
    const float* __restrict__ bias,           // b2l
    const unsigned short* __restrict__ Mw1,   // mw1 fragment-major
    const float* __restrict__ mb1,
    const float* __restrict__ mw2,
    const float* __restrict__ mb2,
    float* __restrict__ outf, int nrows) {
    __shared__ bfx8 ldsW[4096];               // 64 KB
    __shared__ unsigned short hlds[64 * HD];  // 16 KB

    int wid  = threadIdx.x >> 6;
    int lane = threadIdx.x & 63;
    int r  = lane & 15;
    int hi = lane >> 4;
    int ko = hi * 8;
    int row0 = blockIdx.x * 64 + wid * 16;

    int arow  = row0 + r;
    int arowc = min(arow, nrows - 1);

    bfx8 a[4], b[4];
    const unsigned short* Ar = A + (size_t)arowc * HD;
    const unsigned short* Br = B + (size_t)arowc * HD;
#pragma unroll
    for (int kk = 0; kk < 4; ++kk) {
        a[kk] = *(const bfx8*)(Ar + kk * 32 + ko);
        b[kk] = *(const bfx8*)(Br + kk * 32 + ko);
    }

    stage_lds(Wl, &ldsW[0],    32768);
    stage_lds(Wr, &ldsW[2048], 32768);

    float bv[8];
#pragma unroll
    for (int cf = 0; cf < 8; ++cf) bv[cf] = bias[cf * 16 + r];

    fx4 acc[8];
#pragma unroll
    for (int cf = 0; cf < 8; ++cf) acc[cf] = (fx4){0.f, 0.f, 0.f, 0.f};

    __syncthreads();

    // ---- stage 1: h2 = relu(A@Wl^T + B@Wr^T + b2) ----
#pragma unroll
    for (int kk = 0; kk < 4; ++kk) {
#pragma unroll
        for (int cf = 0; cf < 8; ++cf) {
            acc[cf] = __builtin_amdgcn_mfma_f32_16x16x32_bf16(
                a[kk], ldsW[(kk * 8 + cf) * 64 + lane], acc[cf], 0, 0, 0);
            acc[cf] = __builtin_amdgcn_mfma_f32_16x16x32_bf16(
                b[kk], ldsW[2048 + (kk * 8 + cf) * 64 + lane], acc[cf], 0, 0, 0);
        }
    }

#pragma unroll
    for (int cf = 0; cf < 8; ++cf) {
#pragma unroll
        for (int j = 0; j < 4; ++j) {
            int row_l = wid * 16 + hi * 4 + j;        // 0..63 block-local
            unsigned boff = (unsigned)(row_l * 256 + (cf * 16 + r) * 2);
            boff ^= (unsigned)((row_l & 7) << 4);
            *(unsigned short*)((char*)hlds + boff) = f2bf(fmaxf(acc[cf][j] + bv[cf], 0.f));
        }
    }
    __syncthreads();   // all stage-1 LDS reads done; hlds complete

    // reload Mw1 over the Wl region (safe: every wave is past the barrier)
    stage_lds(Mw1, &ldsW[0], 32768);

    // h2 A-frags from hlds (independent of the staging above)
    bfx8 af[4];
    {
        int row_l = wid * 16 + r;
#pragma unroll
        for (int kk = 0; kk < 4; ++kk) {
            unsigned boff = (unsigned)(row_l * 256 + (kk * 32 + ko) * 2);
            boff ^= (unsigned)((row_l & 7) << 4);
            af[kk] = *(const bfx8*)((char*)hlds + boff);
        }
    }

    float m1v[8], m2v[8];
#pragma unroll
    for (int cf = 0; cf < 8; ++cf) {
        m1v[cf] = mb1[cf * 16 + r];
        m2v[cf] = mw2[cf * 16 + r];
    }

    fx4 acc2[8];
#pragma unroll
    for (int cf = 0; cf < 8; ++cf) acc2[cf] = (fx4){0.f, 0.f, 0.f, 0.f};

    __syncthreads();   // drains Mw1 staging

#pragma unroll
    for (int kk = 0; kk < 4; ++kk) {
#pragma unroll
        for (int cf = 0; cf < 8; ++cf)
            acc2[cf] = __builtin_amdgcn_mfma_f32_16x16x32_bf16(
                af[kk], ldsW[(kk * 8 + cf) * 64 + lane], acc2[cf], 0, 0, 0);
    }

    float pd[4] = {0.f, 0.f, 0.f, 0.f};
#pragma unroll
    for (int cf = 0; cf < 8; ++cf) {
#pragma unroll
        for (int j = 0; j < 4; ++j)
            pd[j] += fmaxf(acc2[cf][j] + m1v[cf], 0.f) * m2v[cf];
    }

#pragma unroll
    for (int s = 1; s < 16; s <<= 1) {
#pragma unroll
        for (int j = 0; j < 4; ++j)
            pd[j] += __shfl_xor(pd[j], s, 64);
    }
    if (r == 0) {
        float mb = mb2[0];
#pragma unroll
        for (int j = 0; j < 4; ++j) {
            int row = row0 + hi * 4 + j;
            if (row < nrows) outf[row] = pd[j] + mb;
        }
    }
}

// ---------------- launch ----------------

extern "C" void kernel_launch(void* const* d_in, const int* in_sizes, int n_in,
                              void* d_out, int out_size, void* d_ws, size_t ws_size,
                              hipStream_t stream) {
    const float* x   = (const float*)d_in[0];
    const int*   ei  = (const int*)d_in[1];   // [2,E] int32
    const float* w1l = (const float*)d_in[2];
    const float* b1l = (const float*)d_in[3];
    const float* w1r = (const float*)d_in[4];
    const float* w2l = (const float*)d_in[5];
    const float* b2l = (const float*)d_in[6];
    const float* w2r = (const float*)d_in[7];
    const float* mw1 = (const float*)d_in[8];
    const float* mb1 = (const float*)d_in[9];
    const float* mw2 = (const float*)d_in[10];
    const float* mb2 = (const float*)d_in[11];
    float* out = (float*)d_out;

    const int N = in_sizes[0] / HD;   // 50000
    const int E = in_sizes[1] / 2;    // 1600000
    const int NBK = (N + BKSZ - 1) / BKSZ;   // 196
    const int n8 = N * HD / 8;               // 800000

    char* p = (char*)d_ws;
    auto alloc = [&](size_t bytes) -> char* {
        char* q = p;
        p += (bytes + 255) & ~(size_t)255;
        return q;
    };
    int*            bcnt    = (int*)alloc((size_t)NBK * 4);
    int*            offsets = (int*)alloc(((size_t)N + 1) * 4);
    int*            bpack   = (int*)alloc((size_t)NBK * BCAP * 4);
    int*            sorted  = (int*)alloc((size_t)E * 4);
    unsigned short* Wtb     = (unsigned short*)alloc((size_t)5 * HD * HD * 2);
    unsigned short* xb      = (unsigned short*)alloc((size_t)N * HD * 2);
    unsigned short* bufA    = (unsigned short*)alloc((size_t)N * HD * 2);
    unsigned short* bufB    = (unsigned short*)alloc((size_t)N * HD * 2);

    const unsigned short* W1l = Wtb + 0 * HD * HD;
    const unsigned short* W1r = Wtb + 1 * HD * HD;
    const unsigned short* W2l = Wtb + 2 * HD * HD;
    const unsigned short* W2r = Wtb + 3 * HD * HD;
    const unsigned short* Mw1 = Wtb + 4 * HD * HD;

    const int nbin  = (E + EBIN - 1) / EBIN;  // 782
    const int ncast = (n8 + 255) / 256;       // 3125
    const int nc5   = 40;
    const int gb    = (N + 63) / 64;          // 782
    const int ab    = (N + 3) / 4;            // 12500

    // 7-launch pipeline
    k_zero<<<1, 256, 0, stream>>>(bcnt, NBK);
    k_front<<<nbin + ncast + nc5, 256, 0, stream>>>(
        ei, E, NBK, bcnt, bpack, x, xb, n8,
        w1l, w1r, w2l, w2r, mw1, Wtb, nbin, ncast);
    k_bucket<<<NBK, 512, 0, stream>>>(bpack, bcnt, offsets, sorted, N, E);

    // layer 1
    k_aggr<<<ab, 256, 0, stream>>>(xb, offsets, sorted, bufA, N);
    k_gemm_mfma<<<gb, 256, 0, stream>>>(bufA, xb, W1l, W1r, b1l, bufB, N);
    // layer 2 aggr
    k_aggr<<<ab, 256, 0, stream>>>(bufB, offsets, sorted, bufA, N);
    // layer 2 GEMM + MLP + final, fused
    k_l2_fused<<<gb, 256, 0, stream>>>(bufA, bufB, W2l, W2r, b2l, Mw1, mb1, mw2, mb2,
                                       out, N);
}